// Round 1
// baseline (1394.699 us; speedup 1.0000x reference)
//
// Round 1: correct fused MHA on gfx950.
// Precision plan: Q/K path = split-bf16 (hi/lo, 3-term MFMA) ~= fp32;
// V/PV/O path = plain bf16 MFMA. Softmax fp32 in LDS. attn written fp32.
// attn kernel: 1 WG per (b,h,qtile16); scores[16][2048] fp32 in LDS (128KB),
// K-tiles staged hi/lo with XOR swizzle (^((row&7)<<4)) to kill 16-way bank
// conflicts on ds_read_b128; after softmax, scores repacked in place to
// swizzled bf16 and fed to fused PV (Vt streamed from L2).
#include <hip/hip_runtime.h>

typedef __attribute__((ext_vector_type(4))) float f4;
typedef __attribute__((ext_vector_type(4))) float f32x4;
typedef __attribute__((ext_vector_type(8))) __bf16 bf16x8;
typedef __attribute__((ext_vector_type(8))) unsigned short us8;

__device__ __forceinline__ unsigned short b2u(__bf16 x) {
  union { __bf16 b; unsigned short u; } c; c.b = x; return c.u;
}

// ---------------- elementwise: fp32 -> bf16 hi/lo split, or plain cvt ----
__global__ __launch_bounds__(256) void k_split(const float* __restrict__ in,
                                               unsigned short* __restrict__ hi,
                                               unsigned short* __restrict__ lo, int n) {
  int i = (blockIdx.x * 256 + threadIdx.x) * 8;
  if (i >= n) return;
  f4 a = *(const f4*)(in + i);
  f4 b = *(const f4*)(in + i + 4);
  us8 h, l;
#pragma unroll
  for (int j = 0; j < 4; ++j) {
    float f0 = a[j], f1 = b[j];
    __bf16 h0 = (__bf16)f0, h1 = (__bf16)f1;
    h[j] = b2u(h0); h[j + 4] = b2u(h1);
    l[j] = b2u((__bf16)(f0 - (float)h0));
    l[j + 4] = b2u((__bf16)(f1 - (float)h1));
  }
  *(us8*)(hi + i) = h;
  *(us8*)(lo + i) = l;
}

__global__ __launch_bounds__(256) void k_cvt(const float* __restrict__ in,
                                             unsigned short* __restrict__ out, int n) {
  int i = (blockIdx.x * 256 + threadIdx.x) * 8;
  if (i >= n) return;
  f4 a = *(const f4*)(in + i);
  f4 b = *(const f4*)(in + i + 4);
  us8 h;
#pragma unroll
  for (int j = 0; j < 4; ++j) { h[j] = b2u((__bf16)a[j]); h[j + 4] = b2u((__bf16)b[j]); }
  *(us8*)(out + i) = h;
}

// ---------------- generic NT GEMM: C = A * B^T + bias -------------------
// A: [M][K] bf16 (hi[,lo]); B: [N][K] bf16 (hi[,lo]); K%64==0, tiles 128x128.
// EP 0: out split bf16 hi/lo planes laid out [B,H,S,D] (for Q,K)
// EP 1: out bf16 row-major [M][N]            (for V tmp)
// EP 2: out fp32 row-major [M][N]            (final O proj)
template <bool SPLIT, int EP>
__global__ __launch_bounds__(256) void k_proj(const unsigned short* __restrict__ Ah,
                                              const unsigned short* __restrict__ Al,
                                              const unsigned short* __restrict__ Bh,
                                              const unsigned short* __restrict__ Bl,
                                              const float* __restrict__ bias,
                                              unsigned short* __restrict__ o16a,
                                              unsigned short* __restrict__ o16b,
                                              float* __restrict__ o32,
                                              int Mm, int Nn, int Kk) {
  __shared__ __align__(16) unsigned short sm[SPLIT ? 32768 : 16384];
  char* smb = (char*)sm;
  char* sAh = smb;
  char* sBh = smb + 16384;
  char* sAl = smb + 32768;   // only used when SPLIT
  char* sBl = smb + 49152;
  const int t = threadIdx.x, l = t & 63, w = t >> 6;
  const int wm = w >> 1, wn = w & 1;
  const int m0 = blockIdx.y * 128, n0 = blockIdx.x * 128;
  const int l15 = l & 15, l4 = l >> 4;
  const f32x4 vzero = {0.f, 0.f, 0.f, 0.f};
  f32x4 acc[4][4];
#pragma unroll
  for (int a = 0; a < 4; ++a)
#pragma unroll
    for (int b = 0; b < 4; ++b) acc[a][b] = vzero;

  for (int k0 = 0; k0 < Kk; k0 += 64) {
#pragma unroll
    for (int i = 0; i < 4; ++i) {
      int c = t + 256 * i;
      int row = c >> 3, off = (c & 7) * 8;
      int db = (row * 128 + off * 2) ^ ((row & 7) << 4);
      *(us8*)(sAh + db) = *(const us8*)(Ah + (size_t)(m0 + row) * Kk + k0 + off);
      *(us8*)(sBh + db) = *(const us8*)(Bh + (size_t)(n0 + row) * Kk + k0 + off);
      if constexpr (SPLIT) {
        *(us8*)(sAl + db) = *(const us8*)(Al + (size_t)(m0 + row) * Kk + k0 + off);
        *(us8*)(sBl + db) = *(const us8*)(Bl + (size_t)(n0 + row) * Kk + k0 + off);
      }
    }
    __syncthreads();
#pragma unroll
    for (int ks = 0; ks < 2; ++ks) {
      int kb = ks * 64 + l4 * 16;
      bf16x8 ah[4], al[4], bh[4], bl[4];
#pragma unroll
      for (int mi = 0; mi < 4; ++mi) {
        int row = wm * 64 + mi * 16 + l15;
        int adr = (row * 128 + kb) ^ ((row & 7) << 4);
        ah[mi] = *(const bf16x8*)(sAh + adr);
        if constexpr (SPLIT) al[mi] = *(const bf16x8*)(sAl + adr);
      }
#pragma unroll
      for (int ni = 0; ni < 4; ++ni) {
        int row = wn * 64 + ni * 16 + l15;
        int adr = (row * 128 + kb) ^ ((row & 7) << 4);
        bh[ni] = *(const bf16x8*)(sBh + adr);
        if constexpr (SPLIT) bl[ni] = *(const bf16x8*)(sBl + adr);
      }
#pragma unroll
      for (int mi = 0; mi < 4; ++mi)
#pragma unroll
        for (int ni = 0; ni < 4; ++ni) {
          acc[mi][ni] = __builtin_amdgcn_mfma_f32_16x16x32_bf16(ah[mi], bh[ni], acc[mi][ni], 0, 0, 0);
          if constexpr (SPLIT) {
            acc[mi][ni] = __builtin_amdgcn_mfma_f32_16x16x32_bf16(ah[mi], bl[ni], acc[mi][ni], 0, 0, 0);
            acc[mi][ni] = __builtin_amdgcn_mfma_f32_16x16x32_bf16(al[mi], bh[ni], acc[mi][ni], 0, 0, 0);
          }
        }
    }
    __syncthreads();
  }
  // epilogue: C row = (l>>4)*4+r, col = l&15 within each 16x16 fragment
#pragma unroll
  for (int mi = 0; mi < 4; ++mi)
#pragma unroll
    for (int ni = 0; ni < 4; ++ni) {
      int col = n0 + wn * 64 + ni * 16 + l15;
      float bs = bias[col];
#pragma unroll
      for (int r = 0; r < 4; ++r) {
        int row = m0 + wm * 64 + mi * 16 + l4 * 4 + r;
        float vv = acc[mi][ni][r] + bs;
        if constexpr (EP == 0) {
          int bb = row >> 11, s = row & 2047, h = col >> 6, d = col & 63;
          size_t idx = ((size_t)(bb * 16 + h) * 2048 + s) * 64 + d;
          __bf16 hv = (__bf16)vv;
          o16a[idx] = b2u(hv);
          o16b[idx] = b2u((__bf16)(vv - (float)hv));
        } else if constexpr (EP == 1) {
          o16a[(size_t)row * Nn + col] = b2u((__bf16)vv);
        } else {
          o32[(size_t)row * Nn + col] = vv;
        }
      }
    }
}

// ---------------- V transpose: vtmp[B,S,HD] -> vt[B,H,D,S] ---------------
__global__ __launch_bounds__(256) void k_transpose_v(const unsigned short* __restrict__ vtmp,
                                                     unsigned short* __restrict__ vt) {
  __shared__ __align__(16) unsigned short ts[64 * 72];
  const int t = threadIdx.x;
  const int s0 = blockIdx.x * 64, h = blockIdx.y, b = blockIdx.z;
#pragma unroll
  for (int i = 0; i < 2; ++i) {
    int c = t + 256 * i;
    int row = c >> 3, off = (c & 7) * 8;
    *(us8*)(ts + row * 72 + off) =
        *(const us8*)(vtmp + ((size_t)(b * 2048 + s0 + row)) * 1024 + h * 64 + off);
  }
  __syncthreads();
#pragma unroll
  for (int i = 0; i < 2; ++i) {
    int c = t + 256 * i;
    int drow = c >> 3, soff = (c & 7) * 8;
    us8 v;
#pragma unroll
    for (int j = 0; j < 8; ++j) v[j] = ts[(soff + j) * 72 + drow];
    *(us8*)(vt + ((size_t)((b * 16 + h) * 64 + drow)) * 2048 + s0 + soff) = v;
  }
}

// ---------------- fused attention: QK^T(split) + softmax + attn + PV -----
__global__ __launch_bounds__(256) void k_attn(const unsigned short* __restrict__ Qh,
                                              const unsigned short* __restrict__ Ql,
                                              const unsigned short* __restrict__ Kh,
                                              const unsigned short* __restrict__ Kl,
                                              const unsigned short* __restrict__ Vt,
                                              float* __restrict__ attnO,
                                              unsigned short* __restrict__ oc) {
  __shared__ __align__(16) char smem[16 * 2048 * 4 + 2 * 64 * 64 * 2];  // 144 KB
  float* sS = (float*)smem;               // scores fp32 [16][2048] (first 128KB)
  char* sKh = smem + 131072;              // K hi tile 64x64 bf16, swizzled (8KB)
  char* sKl = smem + 131072 + 8192;       // K lo tile (8KB)
  const int t = threadIdx.x, l = t & 63, w = t >> 6;
  const int l15 = l & 15, l4 = l >> 4;
  const int qt = blockIdx.x, h = blockIdx.y, b = blockIdx.z;
  const int hb = b * 16 + h;
  const size_t headQK = (size_t)hb * 2048 * 64;
  const int q0 = qt * 16;

  // Q fragments (reused for all 32 K-tiles): rows l&15, k = slab*32+(l>>4)*8+j
  bf16x8 qh_f[2], ql_f[2];
  {
    const unsigned short* qp = Qh + headQK + (size_t)(q0 + l15) * 64 + l4 * 8;
    const unsigned short* qp2 = Ql + headQK + (size_t)(q0 + l15) * 64 + l4 * 8;
    qh_f[0] = *(const bf16x8*)(qp);
    qh_f[1] = *(const bf16x8*)(qp + 32);
    ql_f[0] = *(const bf16x8*)(qp2);
    ql_f[1] = *(const bf16x8*)(qp2 + 32);
  }

  // ---- QK^T: 32 K-tiles of 64 positions ----
  for (int kt = 0; kt < 32; ++kt) {
#pragma unroll
    for (int i = 0; i < 2; ++i) {
      int c = t + 256 * i;
      int row = c >> 3, off = (c & 7) * 8;
      int db = (row * 128 + off * 2) ^ ((row & 7) << 4);
      size_t g = headQK + (size_t)(kt * 64 + row) * 64 + off;
      *(us8*)(sKh + db) = *(const us8*)(Kh + g);
      *(us8*)(sKl + db) = *(const us8*)(Kl + g);
    }
    __syncthreads();
    int rowB = w * 16 + l15;
    int rb = rowB * 128, sw = (rowB & 7) << 4;
    int kb = l4 * 16;
    bf16x8 kh0 = *(const bf16x8*)(sKh + ((rb + kb) ^ sw));
    bf16x8 kh1 = *(const bf16x8*)(sKh + ((rb + 64 + kb) ^ sw));
    bf16x8 kl0 = *(const bf16x8*)(sKl + ((rb + kb) ^ sw));
    bf16x8 kl1 = *(const bf16x8*)(sKl + ((rb + 64 + kb) ^ sw));
    f32x4 acc = {0.f, 0.f, 0.f, 0.f};
    acc = __builtin_amdgcn_mfma_f32_16x16x32_bf16(qh_f[0], kh0, acc, 0, 0, 0);
    acc = __builtin_amdgcn_mfma_f32_16x16x32_bf16(qh_f[1], kh1, acc, 0, 0, 0);
    acc = __builtin_amdgcn_mfma_f32_16x16x32_bf16(qh_f[0], kl0, acc, 0, 0, 0);
    acc = __builtin_amdgcn_mfma_f32_16x16x32_bf16(qh_f[1], kl1, acc, 0, 0, 0);
    acc = __builtin_amdgcn_mfma_f32_16x16x32_bf16(ql_f[0], kh0, acc, 0, 0, 0);
    acc = __builtin_amdgcn_mfma_f32_16x16x32_bf16(ql_f[1], kh1, acc, 0, 0, 0);
    int gc = kt * 64 + w * 16 + l15;
#pragma unroll
    for (int r = 0; r < 4; ++r) sS[(l4 * 4 + r) * 2048 + gc] = acc[r] * 0.125f;
    __syncthreads();
  }

  // ---- softmax: 16 threads per row, intra-wave shuffle reduce ----
  float* rowInv = (float*)sKh;
  {
    int row = t >> 4, j0 = t & 15;
    float m = -1e30f;
    for (int i = 0; i < 128; ++i) m = fmaxf(m, sS[row * 2048 + j0 + 16 * i]);
#pragma unroll
    for (int msk = 1; msk < 16; msk <<= 1) m = fmaxf(m, __shfl_xor(m, msk, 64));
    float sum = 0.f;
    for (int i = 0; i < 128; ++i) {
      int idx = row * 2048 + j0 + 16 * i;
      float e = __expf(sS[idx] - m);
      sS[idx] = e;
      sum += e;
    }
#pragma unroll
    for (int msk = 1; msk < 16; msk <<= 1) sum += __shfl_xor(sum, msk, 64);
    if (j0 == 0) rowInv[row] = 1.f / sum;
  }
  __syncthreads();

  // ---- normalize: write fp32 attn to global, repack LDS to swizzled bf16 ----
  // chunk c == q-row c; reads (fp32, bytes [c*8K,+8K)) vs writes (bf16,
  // bytes [c*4K,+4K)) never overlap across chunks; barrier splits in-chunk.
  for (int c = 0; c < 16; ++c) {
    float inv = rowInv[c];
    f4 v0 = *(const f4*)(sS + c * 2048 + t * 8);
    f4 v1 = *(const f4*)(sS + c * 2048 + t * 8 + 4);
    us8 pk;
    f4 w0, w1;
#pragma unroll
    for (int j = 0; j < 4; ++j) {
      float a0 = v0[j] * inv, a1 = v1[j] * inv;
      w0[j] = a0; w1[j] = a1;
      pk[j] = b2u((__bf16)a0);
      pk[j + 4] = b2u((__bf16)a1);
    }
    float* gp = attnO + ((size_t)hb * 2048 + q0 + c) * 2048 + t * 8;
    *(f4*)gp = w0;
    *(f4*)(gp + 4) = w1;
    __syncthreads();
    *(us8*)(smem + ((c * 4096 + t * 16) ^ ((c & 7) << 4))) = pk;
  }
  __syncthreads();

  // ---- PV: out[q,d] = sum_s attn[q,s] * Vt[d,s] ----
  f32x4 accp = {0.f, 0.f, 0.f, 0.f};
  {
    const unsigned short* vrow = Vt + ((size_t)hb * 64 + w * 16 + l15) * 2048 + l4 * 8;
    int ab = l15 * 4096, asw = (l15 & 7) << 4, kob = l4 * 16;
    bf16x8 bcur = *(const bf16x8*)(vrow);
#pragma unroll 4
    for (int ks = 0; ks < 64; ++ks) {
      bf16x8 bnxt = bcur;
      if (ks < 63) bnxt = *(const bf16x8*)(vrow + (ks + 1) * 32);
      bf16x8 a = *(const bf16x8*)(smem + ((ab + ks * 64 + kob) ^ asw));
      accp = __builtin_amdgcn_mfma_f32_16x16x32_bf16(a, bcur, accp, 0, 0, 0);
      bcur = bnxt;
    }
  }
#pragma unroll
  for (int r = 0; r < 4; ++r) {
    int qrow = q0 + l4 * 4 + r;
    oc[((size_t)b * 2048 + qrow) * 1024 + h * 64 + w * 16 + l15] = b2u((__bf16)accp[r]);
  }
}

// ---------------- host ----------------
extern "C" void kernel_launch(void* const* d_in, const int* in_sizes, int n_in,
                              void* d_out, int out_size, void* d_ws, size_t ws_size,
                              hipStream_t stream) {
  const float* q  = (const float*)d_in[0];
  const float* k  = (const float*)d_in[1];
  const float* v  = (const float*)d_in[2];
  const float* Wq = (const float*)d_in[3];
  const float* bq = (const float*)d_in[4];
  const float* Wk = (const float*)d_in[5];
  const float* bk = (const float*)d_in[6];
  const float* Wv = (const float*)d_in[7];
  const float* bv = (const float*)d_in[8];
  const float* Wo = (const float*)d_in[9];
  const float* bo = (const float*)d_in[10];
  float* outp = (float*)d_out;
  float* attnO = outp + (size_t)4096 * 1024;  // out[2,2048,1024] then attn[2,16,2048,2048]

  char* ws = (char*)d_ws;
  size_t off = 0;
  auto alloc = [&](size_t bytes) -> void* {
    off = (off + 255) & ~(size_t)255;
    void* p = ws + off;
    off += bytes;
    return p;
  };
  const size_t SZ_ACT = (size_t)4096 * 1024 * 2;  // 8 MB bf16 plane
  const size_t SZ_W   = (size_t)1024 * 1024 * 2;  // 2 MB bf16 plane
  unsigned short* qs_h = (unsigned short*)alloc(SZ_ACT);
  unsigned short* qs_l = (unsigned short*)alloc(SZ_ACT);
  unsigned short* ks_h = (unsigned short*)alloc(SZ_ACT);
  unsigned short* ks_l = (unsigned short*)alloc(SZ_ACT);
  unsigned short* wq_h = (unsigned short*)alloc(SZ_W);
  unsigned short* wq_l = (unsigned short*)alloc(SZ_W);
  unsigned short* wk_h = (unsigned short*)alloc(SZ_W);
  unsigned short* wk_l = (unsigned short*)alloc(SZ_W);
  unsigned short* vb   = (unsigned short*)alloc(SZ_ACT);
  unsigned short* wv_b = (unsigned short*)alloc(SZ_W);
  unsigned short* wo_b = (unsigned short*)alloc(SZ_W);
  unsigned short* Qh_  = (unsigned short*)alloc(SZ_ACT);
  unsigned short* Ql_  = (unsigned short*)alloc(SZ_ACT);
  unsigned short* Kh_  = (unsigned short*)alloc(SZ_ACT);
  unsigned short* Kl_  = (unsigned short*)alloc(SZ_ACT);
  unsigned short* vtmp = (unsigned short*)alloc(SZ_ACT);
  unsigned short* vt   = (unsigned short*)alloc(SZ_ACT);
  unsigned short* oc   = (unsigned short*)alloc(SZ_ACT);

  k_split<<<2048, 256, 0, stream>>>(q, qs_h, qs_l, 4194304);
  k_split<<<2048, 256, 0, stream>>>(k, ks_h, ks_l, 4194304);
  k_split<<<512, 256, 0, stream>>>(Wq, wq_h, wq_l, 1048576);
  k_split<<<512, 256, 0, stream>>>(Wk, wk_h, wk_l, 1048576);
  k_cvt<<<2048, 256, 0, stream>>>(v, vb, 4194304);
  k_cvt<<<512, 256, 0, stream>>>(Wv, wv_b, 1048576);
  k_cvt<<<512, 256, 0, stream>>>(Wo, wo_b, 1048576);

  dim3 pg(8, 32);  // (N/128, M/128)
  k_proj<true, 0><<<pg, 256, 0, stream>>>(qs_h, qs_l, wq_h, wq_l, bq, Qh_, Ql_, nullptr, 4096, 1024, 1024);
  k_proj<true, 0><<<pg, 256, 0, stream>>>(ks_h, ks_l, wk_h, wk_l, bk, Kh_, Kl_, nullptr, 4096, 1024, 1024);
  k_proj<false, 1><<<pg, 256, 0, stream>>>(vb, nullptr, wv_b, nullptr, bv, vtmp, nullptr, nullptr, 4096, 1024, 1024);
  k_transpose_v<<<dim3(32, 16, 2), 256, 0, stream>>>(vtmp, vt);
  k_attn<<<dim3(128, 16, 2), 256, 0, stream>>>(Qh_, Ql_, Kh_, Kl_, vt, attnO, oc);
  k_proj<false, 2><<<pg, 256, 0, stream>>>(oc, nullptr, wo_b, nullptr, bo, nullptr, nullptr, outp, 4096, 1024, 1024);
}